// Round 13
// baseline (145.567 us; speedup 1.0000x reference)
//
#include <hip/hip_runtime.h>
#include <hip/hip_bf16.h>
#include <cmath>

#define B_ 8
#define W_LEN_ 1000
#define WP 1024          // W padded; rows >= 1000 are exactly 0 -> lsum pad = +24, subtracted at end
#define E_ 100
#define C_ 50
#define CPAD 64          // UO k-padding (2 x K=32 MFMA steps)
#define HP 72            // H row stride (144 B); attn reads bytes 0..127 of each row
#define K_ 3
#define L_ 18000
#define TL 64            // labels per attn block
#define NLBLK ((L_ + TL - 1) / TL)   // 282
#define CWT 16           // w-positions per conv block
#define NSLOT (K_ * (E_ / 4))        // 75 weight slots
#define NWELEM (C_ * E_ * K_)        // 15000 conv_w floats
#define NCONVBLK 512                 // conv blocks (64 wx x 8 b)
#define NPREPBLK 512                 // UO-prep blocks (grid-strided), same dispatch

typedef __attribute__((ext_vector_type(8))) short bf16x8;   // 8 bf16 = 4 VGPRs
typedef __attribute__((ext_vector_type(4))) short bf16x4;   // 4 bf16 = 2 VGPRs
typedef __attribute__((ext_vector_type(4))) float f32x4;

static __device__ __forceinline__ float bf2f(short s) {
    return __uint_as_float(((unsigned)(unsigned short)s) << 16);
}

// ---------------- conv_prep: block-level fusion of conv and UO prep (R11-proven) ----------------
__global__ __launch_bounds__(256) void conv_prep_kernel(
    const int* __restrict__ x,          // (B, W)
    const float* __restrict__ W_embed,  // (V, E)
    const float* __restrict__ conv_w,   // (C, E, K) fp32
    const float* __restrict__ conv_b,   // (C,)
    const float* __restrict__ u_w,      // (L, C) fp32
    const float* __restrict__ out_w,    // (L, C) fp32
    __hip_bfloat16* __restrict__ H,     // (B, WP, HP)
    __hip_bfloat16* __restrict__ UO)    // (2, L, CPAD)
{
    __shared__ float4 emb_s[(CWT + 2) * (E_ / 4)];   // 18 rows x 25 f4 = 7.2 KB
    __shared__ bf16x4 wS[NSLOT * C_];                // 75 x 50 x 8B = 30 KB

    const int gid = blockIdx.x;
    const int tid = threadIdx.x;

    if (gid >= NCONVBLK) {
        // ---- UO prep blocks: coalesced, bit-identical rounding to the old prep pass ----
        const int stride = NPREPBLK * 256;
        for (int idx = (gid - NCONVBLK) * 256 + tid; idx < 2 * L_ * CPAD; idx += stride) {
            int cu = idx & (CPAD - 1);
            int l  = (idx >> 6) % L_;
            int m  = idx / (L_ * CPAD);
            const float* src = m ? out_w : u_w;
            float v = (cu < C_) ? src[(size_t)l * C_ + cu] : 0.f;
            UO[idx] = __float2bfloat16(v);
        }
        return;
    }

    // ---- conv path ----
    const int b  = gid >> 6;            // 0..7
    const int w0 = (gid & 63) * CWT;

    // weights: contiguous coalesced fp32 read -> bf16 -> scattered LDS write (cwTs layout)
    short* wS_s = (short*)wS;
    for (int i = tid; i < NWELEM; i += 256) {          // 59 iters, stride-1 coalesced
        int c = i / (E_ * K_);
        int r = i - c * (E_ * K_);
        int e = r / K_;
        int k = r - e * K_;
        __hip_bfloat16 h = __float2bfloat16(conv_w[i]);
        wS_s[((k * (E_ / 4) + (e >> 2)) * C_ + c) * 4 + (e & 3)] = *reinterpret_cast<short*>(&h);
    }

    for (int i = tid; i < (CWT + 2) * (E_ / 4); i += 256) {
        int row = i / (E_ / 4);
        int e4  = i % (E_ / 4);
        int ws  = w0 - 1 + row;
        float4 v = make_float4(0.f, 0.f, 0.f, 0.f);
        if ((unsigned)ws < (unsigned)W_LEN_)
            v = ((const float4*)(W_embed + (size_t)x[b * W_LEN_ + ws] * E_))[e4];
        emb_s[i] = v;
    }
    __syncthreads();

    const int c  = tid & 63;
    const int wq = tid >> 6;          // 0..3
    const int cc = (c < C_) ? c : 0;  // dead lanes compute c=0, write 0

    f32x4 acc[4];
    const float bias = conv_b[cc];
    #pragma unroll
    for (int j = 0; j < 4; j++) acc[j] = (f32x4){bias, 0.f, 0.f, 0.f};

    const float4* eb = &emb_s[wq * 4 * (E_ / 4)];

    #pragma unroll 5
    for (int i = 0; i < E_ / 4; i++) {
        bf16x4 kb0 = wS[i * C_ + cc];
        bf16x4 kb1 = wS[(25 + i) * C_ + cc];
        bf16x4 kb2 = wS[(50 + i) * C_ + cc];
        float4 k0 = make_float4(bf2f(kb0[0]), bf2f(kb0[1]), bf2f(kb0[2]), bf2f(kb0[3]));
        float4 k1 = make_float4(bf2f(kb1[0]), bf2f(kb1[1]), bf2f(kb1[2]), bf2f(kb1[3]));
        float4 k2 = make_float4(bf2f(kb2[0]), bf2f(kb2[1]), bf2f(kb2[2]), bf2f(kb2[3]));
        float4 e0 = eb[i],       e1 = eb[25 + i],  e2 = eb[50 + i];
        float4 e3 = eb[75 + i],  e4 = eb[100 + i], e5 = eb[125 + i];
        acc[0].x += e0.x*k0.x + e1.x*k1.x + e2.x*k2.x;
        acc[0].y += e0.y*k0.y + e1.y*k1.y + e2.y*k2.y;
        acc[0].z += e0.z*k0.z + e1.z*k1.z + e2.z*k2.z;
        acc[0].w += e0.w*k0.w + e1.w*k1.w + e2.w*k2.w;
        acc[1].x += e1.x*k0.x + e2.x*k1.x + e3.x*k2.x;
        acc[1].y += e1.y*k0.y + e2.y*k1.y + e3.y*k2.y;
        acc[1].z += e1.z*k0.z + e2.z*k1.z + e3.z*k2.z;
        acc[1].w += e1.w*k0.w + e2.w*k1.w + e3.w*k2.w;
        acc[2].x += e2.x*k0.x + e3.x*k1.x + e4.x*k2.x;
        acc[2].y += e2.y*k0.y + e3.y*k1.y + e4.y*k2.y;
        acc[2].z += e2.z*k0.z + e3.z*k1.z + e4.z*k2.z;
        acc[2].w += e2.w*k0.w + e3.w*k1.w + e4.w*k2.w;
        acc[3].x += e3.x*k0.x + e4.x*k1.x + e5.x*k2.x;
        acc[3].y += e3.y*k0.y + e4.y*k1.y + e5.y*k2.y;
        acc[3].z += e3.z*k0.z + e4.z*k1.z + e5.z*k2.z;
        acc[3].w += e3.w*k0.w + e4.w*k1.w + e5.w*k2.w;
    }

    #pragma unroll
    for (int j = 0; j < 4; j++) {
        int w = w0 + wq * 4 + j;
        float v = 0.f;
        if (c < C_ && w < W_LEN_)
            v = tanhf((acc[j].x + acc[j].z) + (acc[j].y + acc[j].w));
        __hip_bfloat16* row = H + ((size_t)b * WP + w) * HP;
        row[c] = __float2bfloat16(v);   // c in 50..63 / w >= 1000 write 0; cols 64..71 never read
    }
}

// ---------------- attn: direct-from-L2 dual-GEMM + fused softmax-pool ----------------
// R12 structure (packed-f32 softmax, XCD swizzle, barrier-free) + DEPTH-2 prefetch:
// 3 rotating buffers B0/B1/B2, loads issued 2 steps ahead of use (covers ~300-400 cyc
// >= loaded-L2 latency; depth-1 covered only ~150-200). No rotate-copies. VGPR ~92
// stays at 5 waves/SIMD cap -- measured residency ~2.3/SIMD, so cap non-binding
// (R7's depth-3 failure was the 156-VGPR cliff, not depth).
__global__ __launch_bounds__(256) void attn_kernel(
    const __hip_bfloat16* __restrict__ H,   // (B, WP, HP)
    const __hip_bfloat16* __restrict__ UO,  // (2, L, CPAD)
    const float* __restrict__ out_b,        // (L,)
    float* __restrict__ out)                // (B, L)
{
    __shared__ float2 red[2][TL];           // 1 KB

    const int flat = blockIdx.y * gridDim.x + blockIdx.x;          // dispatch order, x fastest
    const int g    = (flat & 7) * ((NLBLK * B_) / 8) + (flat >> 3); // bijective XCD chunking
    const int b  = g & 7;
    const int l0 = (g >> 3) * TL;
    const int tid  = threadIdx.x;
    const int lane = tid & 63;
    const int wid  = tid >> 6;
    const int mi = wid & 1, ni = wid >> 1;
    const int col = lane & 15, quad = lane >> 4;

    // loop-invariant A-fragments for U and O
    bf16x8 Uf[2][2], Of[2][2];
    #pragma unroll
    for (int mt = 0; mt < 2; mt++) {
        int l = l0 + mi * 32 + mt * 16 + col;
        if (l >= L_) l = L_ - 1;                       // clamp; result discarded
        const __hip_bfloat16* up = UO + (size_t)l * CPAD + quad * 8;
        const __hip_bfloat16* op = up + (size_t)L_ * CPAD;
        #pragma unroll
        for (int st = 0; st < 2; st++) {
            Uf[mt][st] = *(const bf16x8*)(up + st * 32);
            Of[mt][st] = *(const bf16x8*)(op + st * 32);
        }
    }

    f32x4 lsum[2] = {{0.f,0.f,0.f,0.f},{0.f,0.f,0.f,0.f}};
    f32x4 num [2] = {{0.f,0.f,0.f,0.f},{0.f,0.f,0.f,0.f}};
    const f32x4 zero = {0.f, 0.f, 0.f, 0.f};
    const f32x4 vlog2e = {1.4426950408889634f, 1.4426950408889634f,
                          1.4426950408889634f, 1.4426950408889634f};

    // per-lane B-frag base: row = ni*32 + nt*16 + col, byte = quad*16 + st*64 within 144B row
    const char* gB = (const char*)(H + (size_t)b * WP * HP)
                   + ((size_t)(ni * 32 + col) * HP + quad * 8) * 2;

#define WSTEP (64 * HP * 2)   // 9216 B: one 64-w step

#define LOADF(Bf, gp)                                                            \
    {                                                                            \
        const char* _g = (gp);                                                   \
        _Pragma("unroll")                                                        \
        for (int nt = 0; nt < 2; nt++)                                           \
            _Pragma("unroll")                                                    \
            for (int st = 0; st < 2; st++)                                       \
                Bf[nt][st] = *(const bf16x8*)(_g + nt * (16 * HP * 2) + st * 64);\
    }

#define COMPUTE(Bf)                                                              \
    _Pragma("unroll")                                                            \
    for (int nt = 0; nt < 2; nt++) {                                             \
        _Pragma("unroll")                                                        \
        for (int mt = 0; mt < 2; mt++) {                                         \
            __builtin_amdgcn_s_setprio(1);                                       \
            f32x4 S = __builtin_amdgcn_mfma_f32_16x16x32_bf16(Uf[mt][0], Bf[nt][0], zero, 0, 0, 0); \
            S       = __builtin_amdgcn_mfma_f32_16x16x32_bf16(Uf[mt][1], Bf[nt][1], S,    0, 0, 0); \
            f32x4 T = __builtin_amdgcn_mfma_f32_16x16x32_bf16(Of[mt][0], Bf[nt][0], zero, 0, 0, 0); \
            T       = __builtin_amdgcn_mfma_f32_16x16x32_bf16(Of[mt][1], Bf[nt][1], T,    0, 0, 0); \
            __builtin_amdgcn_s_setprio(0);                                       \
            f32x4 Sx = S * vlog2e;            /* packed v_pk_mul_f32 */          \
            f32x4 p;                                                             \
            _Pragma("unroll")                                                    \
            for (int r = 0; r < 4; r++)                                          \
                p[r] = __builtin_amdgcn_exp2f(Sx[r]);                            \
            lsum[mt] = lsum[mt] + p;          /* packed v_pk_add_f32 */          \
            num [mt] = num [mt] + p * T;      /* packed v_pk_fma_f32 */          \
        }                                                                        \
    }

    // depth-2 pipeline: 16 steps; loop covers steps 0..11, explicit tail 12..15.
    bf16x8 B0[2][2], B1[2][2], B2[2][2];
    LOADF(B0, gB)                           // step 0
    LOADF(B1, gB + WSTEP)                   // step 1

    #pragma unroll 1
    for (int t = 0; t < 12; t += 3) {
        LOADF(B2, gB + 2 * WSTEP)           // step t+2
        COMPUTE(B0)                         // step t
        LOADF(B0, gB + 3 * WSTEP)           // step t+3
        COMPUTE(B1)                         // step t+1
        LOADF(B1, gB + 4 * WSTEP)           // step t+4
        COMPUTE(B2)                         // step t+2
        gB += 3 * WSTEP;
    }
    // tail: B0=step12, B1=step13 already loaded; steps 14,15 remain
    LOADF(B2, gB + 2 * WSTEP)               // step 14
    COMPUTE(B0)                             // step 12
    LOADF(B0, gB + 3 * WSTEP)               // step 15
    COMPUTE(B1)                             // step 13
    COMPUTE(B2)                             // step 14
    COMPUTE(B0)                             // step 15

    // reduce the 16 w-cols held per (quad): xor-butterfly on lane bits 0-3
    #pragma unroll
    for (int mt = 0; mt < 2; mt++) {
        #pragma unroll
        for (int r = 0; r < 4; r++) {
            float ls = lsum[mt][r], nm = num[mt][r];
            #pragma unroll
            for (int d = 1; d < 16; d <<= 1) {
                ls += __shfl_xor(ls, d, 64);
                nm += __shfl_xor(nm, d, 64);
            }
            if (col == 0)
                red[ni][mi * 32 + mt * 16 + quad * 4 + r] = make_float2(ls, nm);
        }
    }
    __syncthreads();

    if (tid < TL) {
        int l = l0 + tid;
        if (l < L_) {
            float2 p0 = red[0][tid], p1 = red[1][tid];
            float z = (p0.y + p1.y) / (p0.x + p1.x - (float)(WP - W_LEN_)) + out_b[l];
            out[(size_t)b * L_ + l] = 1.f / (1.f + __expf(-z));
        }
    }
}

extern "C" void kernel_launch(void* const* d_in, const int* in_sizes, int n_in,
                              void* d_out, int out_size, void* d_ws, size_t ws_size,
                              hipStream_t stream) {
    const int*   x       = (const int*)  d_in[0];
    const float* W_embed = (const float*)d_in[1];
    const float* conv_w  = (const float*)d_in[2];
    const float* conv_b  = (const float*)d_in[3];
    const float* u_w     = (const float*)d_in[4];
    const float* out_w   = (const float*)d_in[5];
    const float* out_b   = (const float*)d_in[6];
    float* out = (float*)d_out;

    char* ws = (char*)d_ws;
    __hip_bfloat16* H  = (__hip_bfloat16*)ws;                 // 8*1024*72*2 = 1,179,648 B
    __hip_bfloat16* UO = (__hip_bfloat16*)(ws + 1179648);     // 2*18000*64*2 = 4,608,000 B

    {
        conv_prep_kernel<<<dim3(NCONVBLK + NPREPBLK), 256, 0, stream>>>(
            x, W_embed, conv_w, conv_b, u_w, out_w, H, UO);
    }
    {
        dim3 grid(NLBLK, B_);
        attn_kernel<<<grid, 256, 0, stream>>>(H, UO, out_b, out);
    }
}

// Round 14
// 139.734 us; speedup vs baseline: 1.0417x; 1.0417x over previous
//
#include <hip/hip_runtime.h>
#include <hip/hip_bf16.h>
#include <cmath>

#define B_ 8
#define W_LEN_ 1000
#define WP 1024          // W padded; rows >= 1000 are exactly 0 -> lsum pad = +24, subtracted at end
#define E_ 100
#define C_ 50
#define CPAD 64          // UO k-padding (2 x K=32 MFMA steps)
#define HP 72            // H row stride (144 B); attn reads bytes 0..127 of each row
#define K_ 3
#define L_ 18000
#define TL 64            // labels per attn block
#define NLBLK ((L_ + TL - 1) / TL)   // 282
#define CWT 16           // w-positions per conv block
#define NSLOT (K_ * (E_ / 4))        // 75 weight slots
#define NWELEM (C_ * E_ * K_)        // 15000 conv_w floats
#define NCONVBLK 512                 // conv blocks (64 wx x 8 b)
#define NPREPBLK 512                 // UO-prep blocks (grid-strided), same dispatch

typedef __attribute__((ext_vector_type(8))) short bf16x8;   // 8 bf16 = 4 VGPRs
typedef __attribute__((ext_vector_type(4))) short bf16x4;   // 4 bf16 = 2 VGPRs
typedef __attribute__((ext_vector_type(4))) float f32x4;

static __device__ __forceinline__ float bf2f(short s) {
    return __uint_as_float(((unsigned)(unsigned short)s) << 16);
}

// ---------------- conv_prep: block-level fusion of conv and UO prep (R11-proven) ----------------
__global__ __launch_bounds__(256) void conv_prep_kernel(
    const int* __restrict__ x,          // (B, W)
    const float* __restrict__ W_embed,  // (V, E)
    const float* __restrict__ conv_w,   // (C, E, K) fp32
    const float* __restrict__ conv_b,   // (C,)
    const float* __restrict__ u_w,      // (L, C) fp32
    const float* __restrict__ out_w,    // (L, C) fp32
    __hip_bfloat16* __restrict__ H,     // (B, WP, HP)
    __hip_bfloat16* __restrict__ UO)    // (2, L, CPAD)
{
    __shared__ float4 emb_s[(CWT + 2) * (E_ / 4)];   // 18 rows x 25 f4 = 7.2 KB
    __shared__ bf16x4 wS[NSLOT * C_];                // 75 x 50 x 8B = 30 KB

    const int gid = blockIdx.x;
    const int tid = threadIdx.x;

    if (gid >= NCONVBLK) {
        // ---- UO prep blocks: coalesced, bit-identical rounding to the old prep pass ----
        const int stride = NPREPBLK * 256;
        for (int idx = (gid - NCONVBLK) * 256 + tid; idx < 2 * L_ * CPAD; idx += stride) {
            int cu = idx & (CPAD - 1);
            int l  = (idx >> 6) % L_;
            int m  = idx / (L_ * CPAD);
            const float* src = m ? out_w : u_w;
            float v = (cu < C_) ? src[(size_t)l * C_ + cu] : 0.f;
            UO[idx] = __float2bfloat16(v);
        }
        return;
    }

    // ---- conv path ----
    const int b  = gid >> 6;            // 0..7
    const int w0 = (gid & 63) * CWT;

    // weights: contiguous coalesced fp32 read -> bf16 -> scattered LDS write (cwTs layout)
    short* wS_s = (short*)wS;
    for (int i = tid; i < NWELEM; i += 256) {          // 59 iters, stride-1 coalesced
        int c = i / (E_ * K_);
        int r = i - c * (E_ * K_);
        int e = r / K_;
        int k = r - e * K_;
        __hip_bfloat16 h = __float2bfloat16(conv_w[i]);
        wS_s[((k * (E_ / 4) + (e >> 2)) * C_ + c) * 4 + (e & 3)] = *reinterpret_cast<short*>(&h);
    }

    for (int i = tid; i < (CWT + 2) * (E_ / 4); i += 256) {
        int row = i / (E_ / 4);
        int e4  = i % (E_ / 4);
        int ws  = w0 - 1 + row;
        float4 v = make_float4(0.f, 0.f, 0.f, 0.f);
        if ((unsigned)ws < (unsigned)W_LEN_)
            v = ((const float4*)(W_embed + (size_t)x[b * W_LEN_ + ws] * E_))[e4];
        emb_s[i] = v;
    }
    __syncthreads();

    const int c  = tid & 63;
    const int wq = tid >> 6;          // 0..3
    const int cc = (c < C_) ? c : 0;  // dead lanes compute c=0, write 0

    f32x4 acc[4];
    const float bias = conv_b[cc];
    #pragma unroll
    for (int j = 0; j < 4; j++) acc[j] = (f32x4){bias, 0.f, 0.f, 0.f};

    const float4* eb = &emb_s[wq * 4 * (E_ / 4)];

    #pragma unroll 5
    for (int i = 0; i < E_ / 4; i++) {
        bf16x4 kb0 = wS[i * C_ + cc];
        bf16x4 kb1 = wS[(25 + i) * C_ + cc];
        bf16x4 kb2 = wS[(50 + i) * C_ + cc];
        float4 k0 = make_float4(bf2f(kb0[0]), bf2f(kb0[1]), bf2f(kb0[2]), bf2f(kb0[3]));
        float4 k1 = make_float4(bf2f(kb1[0]), bf2f(kb1[1]), bf2f(kb1[2]), bf2f(kb1[3]));
        float4 k2 = make_float4(bf2f(kb2[0]), bf2f(kb2[1]), bf2f(kb2[2]), bf2f(kb2[3]));
        float4 e0 = eb[i],       e1 = eb[25 + i],  e2 = eb[50 + i];
        float4 e3 = eb[75 + i],  e4 = eb[100 + i], e5 = eb[125 + i];
        acc[0].x += e0.x*k0.x + e1.x*k1.x + e2.x*k2.x;
        acc[0].y += e0.y*k0.y + e1.y*k1.y + e2.y*k2.y;
        acc[0].z += e0.z*k0.z + e1.z*k1.z + e2.z*k2.z;
        acc[0].w += e0.w*k0.w + e1.w*k1.w + e2.w*k2.w;
        acc[1].x += e1.x*k0.x + e2.x*k1.x + e3.x*k2.x;
        acc[1].y += e1.y*k0.y + e2.y*k1.y + e3.y*k2.y;
        acc[1].z += e1.z*k0.z + e2.z*k1.z + e3.z*k2.z;
        acc[1].w += e1.w*k0.w + e2.w*k1.w + e3.w*k2.w;
        acc[2].x += e2.x*k0.x + e3.x*k1.x + e4.x*k2.x;
        acc[2].y += e2.y*k0.y + e3.y*k1.y + e4.y*k2.y;
        acc[2].z += e2.z*k0.z + e3.z*k1.z + e4.z*k2.z;
        acc[2].w += e2.w*k0.w + e3.w*k1.w + e4.w*k2.w;
        acc[3].x += e3.x*k0.x + e4.x*k1.x + e5.x*k2.x;
        acc[3].y += e3.y*k0.y + e4.y*k1.y + e5.y*k2.y;
        acc[3].z += e3.z*k0.z + e4.z*k1.z + e5.z*k2.z;
        acc[3].w += e3.w*k0.w + e4.w*k1.w + e5.w*k2.w;
    }

    #pragma unroll
    for (int j = 0; j < 4; j++) {
        int w = w0 + wq * 4 + j;
        float v = 0.f;
        if (c < C_ && w < W_LEN_)
            v = tanhf((acc[j].x + acc[j].z) + (acc[j].y + acc[j].w));
        __hip_bfloat16* row = H + ((size_t)b * WP + w) * HP;
        row[c] = __float2bfloat16(v);   // c in 50..63 / w >= 1000 write 0; cols 64..71 never read
    }
}

// ---------------- attn: direct-from-L2 dual-GEMM + fused softmax-pool (R12-exact, session best) ----------------
// Grid (NLBLK, B). 4 waves: (mi,ni); wave tile 32 lbl x 32 w. HP=72 (144B rows).
// XCD-aware remap (T1): FETCH at single-copy ideal (6.98MB). H L2-resident: B-frags
// straight from global (16B). Depth-1 Ba/Bb double-buffer (depth-2/3 regress: VGPR
// footprint dominates -- R7 156VGPR=107us, R13 88VGPR=70us, R12 76VGPR=56.7us).
// Packed-f32 softmax (v_pk_mul/add/fma pairs, -7%); exp via v_mul+v_exp; barrier-free.
__global__ __launch_bounds__(256) void attn_kernel(
    const __hip_bfloat16* __restrict__ H,   // (B, WP, HP)
    const __hip_bfloat16* __restrict__ UO,  // (2, L, CPAD)
    const float* __restrict__ out_b,        // (L,)
    float* __restrict__ out)                // (B, L)
{
    __shared__ float2 red[2][TL];           // 1 KB

    const int flat = blockIdx.y * gridDim.x + blockIdx.x;          // dispatch order, x fastest
    const int g    = (flat & 7) * ((NLBLK * B_) / 8) + (flat >> 3); // bijective XCD chunking
    const int b  = g & 7;
    const int l0 = (g >> 3) * TL;
    const int tid  = threadIdx.x;
    const int lane = tid & 63;
    const int wid  = tid >> 6;
    const int mi = wid & 1, ni = wid >> 1;
    const int col = lane & 15, quad = lane >> 4;

    // loop-invariant A-fragments for U and O
    bf16x8 Uf[2][2], Of[2][2];
    #pragma unroll
    for (int mt = 0; mt < 2; mt++) {
        int l = l0 + mi * 32 + mt * 16 + col;
        if (l >= L_) l = L_ - 1;                       // clamp; result discarded
        const __hip_bfloat16* up = UO + (size_t)l * CPAD + quad * 8;
        const __hip_bfloat16* op = up + (size_t)L_ * CPAD;
        #pragma unroll
        for (int st = 0; st < 2; st++) {
            Uf[mt][st] = *(const bf16x8*)(up + st * 32);
            Of[mt][st] = *(const bf16x8*)(op + st * 32);
        }
    }

    f32x4 lsum[2] = {{0.f,0.f,0.f,0.f},{0.f,0.f,0.f,0.f}};
    f32x4 num [2] = {{0.f,0.f,0.f,0.f},{0.f,0.f,0.f,0.f}};
    const f32x4 zero = {0.f, 0.f, 0.f, 0.f};
    const f32x4 vlog2e = {1.4426950408889634f, 1.4426950408889634f,
                          1.4426950408889634f, 1.4426950408889634f};

    // per-lane B-frag base: row = ni*32 + nt*16 + col, byte = quad*16 + st*64 within 144B row
    const char* gB = (const char*)(H + (size_t)b * WP * HP)
                   + ((size_t)(ni * 32 + col) * HP + quad * 8) * 2;

#define WSTEP (64 * HP * 2)   // 9216 B: one 64-w step

#define LOADF(Bf, gp)                                                            \
    {                                                                            \
        const char* _g = (gp);                                                   \
        _Pragma("unroll")                                                        \
        for (int nt = 0; nt < 2; nt++)                                           \
            _Pragma("unroll")                                                    \
            for (int st = 0; st < 2; st++)                                       \
                Bf[nt][st] = *(const bf16x8*)(_g + nt * (16 * HP * 2) + st * 64);\
    }

#define COMPUTE(Bf)                                                              \
    _Pragma("unroll")                                                            \
    for (int nt = 0; nt < 2; nt++) {                                             \
        _Pragma("unroll")                                                        \
        for (int mt = 0; mt < 2; mt++) {                                         \
            __builtin_amdgcn_s_setprio(1);                                       \
            f32x4 S = __builtin_amdgcn_mfma_f32_16x16x32_bf16(Uf[mt][0], Bf[nt][0], zero, 0, 0, 0); \
            S       = __builtin_amdgcn_mfma_f32_16x16x32_bf16(Uf[mt][1], Bf[nt][1], S,    0, 0, 0); \
            f32x4 T = __builtin_amdgcn_mfma_f32_16x16x32_bf16(Of[mt][0], Bf[nt][0], zero, 0, 0, 0); \
            T       = __builtin_amdgcn_mfma_f32_16x16x32_bf16(Of[mt][1], Bf[nt][1], T,    0, 0, 0); \
            __builtin_amdgcn_s_setprio(0);                                       \
            f32x4 Sx = S * vlog2e;            /* packed v_pk_mul_f32 */          \
            f32x4 p;                                                             \
            _Pragma("unroll")                                                    \
            for (int r = 0; r < 4; r++)                                          \
                p[r] = __builtin_amdgcn_exp2f(Sx[r]);                            \
            lsum[mt] = lsum[mt] + p;          /* packed v_pk_add_f32 */          \
            num [mt] = num [mt] + p * T;      /* packed v_pk_fma_f32 */          \
        }                                                                        \
    }

    bf16x8 Ba[2][2], Bb[2][2];
    LOADF(Ba, gB)                       // step 0

    #pragma unroll 1
    for (int t = 0; t < WP / 64; t += 2) {
        LOADF(Bb, gB + WSTEP)           // prefetch step t+1 (always valid: 16 steps, even)
        COMPUTE(Ba)                     // step t
        if (t + 2 < WP / 64)
            LOADF(Ba, gB + 2 * WSTEP)   // prefetch step t+2
        COMPUTE(Bb)                     // step t+1
        gB += 2 * WSTEP;
    }

    // reduce the 16 w-cols held per (quad): xor-butterfly on lane bits 0-3
    #pragma unroll
    for (int mt = 0; mt < 2; mt++) {
        #pragma unroll
        for (int r = 0; r < 4; r++) {
            float ls = lsum[mt][r], nm = num[mt][r];
            #pragma unroll
            for (int d = 1; d < 16; d <<= 1) {
                ls += __shfl_xor(ls, d, 64);
                nm += __shfl_xor(nm, d, 64);
            }
            if (col == 0)
                red[ni][mi * 32 + mt * 16 + quad * 4 + r] = make_float2(ls, nm);
        }
    }
    __syncthreads();

    if (tid < TL) {
        int l = l0 + tid;
        if (l < L_) {
            float2 p0 = red[0][tid], p1 = red[1][tid];
            float z = (p0.y + p1.y) / (p0.x + p1.x - (float)(WP - W_LEN_)) + out_b[l];
            out[(size_t)b * L_ + l] = 1.f / (1.f + __expf(-z));
        }
    }
}

extern "C" void kernel_launch(void* const* d_in, const int* in_sizes, int n_in,
                              void* d_out, int out_size, void* d_ws, size_t ws_size,
                              hipStream_t stream) {
    const int*   x       = (const int*)  d_in[0];
    const float* W_embed = (const float*)d_in[1];
    const float* conv_w  = (const float*)d_in[2];
    const float* conv_b  = (const float*)d_in[3];
    const float* u_w     = (const float*)d_in[4];
    const float* out_w   = (const float*)d_in[5];
    const float* out_b   = (const float*)d_in[6];
    float* out = (float*)d_out;

    char* ws = (char*)d_ws;
    __hip_bfloat16* H  = (__hip_bfloat16*)ws;                 // 8*1024*72*2 = 1,179,648 B
    __hip_bfloat16* UO = (__hip_bfloat16*)(ws + 1179648);     // 2*18000*64*2 = 4,608,000 B

    {
        conv_prep_kernel<<<dim3(NCONVBLK + NPREPBLK), 256, 0, stream>>>(
            x, W_embed, conv_w, conv_b, u_w, out_w, H, UO);
    }
    {
        dim3 grid(NLBLK, B_);
        attn_kernel<<<grid, 256, 0, stream>>>(H, UO, out_b, out);
    }
}